// Round 3
// baseline (95.826 us; speedup 1.0000x reference)
//
#include <hip/hip_runtime.h>

#define IN_F 4096
#define OUT_F 11008
#define M 8
#define S_SLICES 16
#define KPS (IN_F / S_SLICES)     // 256 k-values per slice (one wave's share)
#define RPSL (KPS / 8)            // 32 packed qweight rows per slice
#define STEPS (KPS / 32)          // 8 MFMA K-steps per wave

typedef __bf16 bf16x8 __attribute__((ext_vector_type(8)));
typedef float  f32x4  __attribute__((ext_vector_type(4)));

// Pack two fp32 into one dword of 2 bf16 by truncation: one v_perm_b32.
// perm concat = {a bytes 4..7, b bytes 0..3}; sel 0x07060302 picks
// [b.b2, b.b3, a.b2, a.b3] = (lo>>16) | (hi & 0xffff0000).
__device__ __forceinline__ unsigned pack_bf_trunc(float lo, float hi) {
    return __builtin_amdgcn_perm(__float_as_uint(hi), __float_as_uint(lo),
                                 0x07060302u);
}

// ---------------- fused MFMA partial GEMM ----------------
// P[slice][r][col] = sum_{k in slice} (w[k][col] - z_col) * bf16(x[r][k])
//
// Grid (172,16)x256: 11008 waves = 10.75 waves/SIMD (the round-1/2 fused
// kernel's 2.7 waves/SIMD was the regression: latency unhidden). Each wave =
// 16 cols x 256 k (8 MFMA steps). A block's 4 waves cover 64 consecutive
// cols, consuming whole 128B qweight lines; the block's 8KB x-slice is shared
// by all 4 waves (L1-resident).
//
// MFMA 16x16x32 bf16, layouts m89/m91-verified:
//   A[m=lane&15][k=quad*8+j], B[k=quad*8+j][n=lane&15], D[row=quad*4+reg][col=lane&15].
//   B-frag k-run of 8 == nibbles of ONE qweight int32 (LSB-first).
// A pad rows 8..15 alias rows 0..7 (t&7): duplicate D rows (quads 2,3) are
// simply not written; duplicate loads coalesce.
// z_col is folded into B (per-lane constant) -> no rowsum pass; fp32->bf16
// conversion is inline (v_perm) -> no convert pass.
__global__ __launch_bounds__(256, 4) void gptq_mfma_fused(
    const int*   __restrict__ qw,   // (512, OUT_F)
    const float* __restrict__ x,    // (8, IN_F)
    const int*   __restrict__ qz,   // (1, OUT_F/8)
    float*       __restrict__ P)    // (S_SLICES, M, OUT_F)
{
    const int lane = (int)threadIdx.x & 63;
    const int wv   = (int)threadIdx.x >> 6;            // wave 0..3 = col subtile
    const int t    = lane & 15;                        // = m (A) = n (B) = col (D)
    const int quad = lane >> 4;                        // 0..3
    const int col  = ((int)blockIdx.x * 4 + wv) * 16 + t;  // 172*4*16 = 11008
    const int i0   = (int)blockIdx.y * RPSL;           // first packed row of slice
    const int kb   = (int)blockIdx.y * KPS;            // first k of slice

    // zero point for this column (per-lane constant), +1 per GPTQ convention
    const float zf = (float)(((qz[col >> 3] >> ((col & 7) * 4)) & 15) + 1);

    // Prefetch the wave's whole qweight strip: 8 dword loads in flight,
    // HBM latency paid once (and hidden by 8 resident waves/SIMD).
    int qv[STEPS];
    const int* qp = qw + (size_t)(i0 + quad) * OUT_F + col;
#pragma unroll
    for (int s = 0; s < STEPS; ++s)
        qv[s] = qp[(size_t)s * 4 * OUT_F];             // row i0 + s*4 + quad

    // A source: row t&7, k = kb + quad*8 + s*32. In-loop byte offsets
    // s*128(+16) B fit the 13-bit signed global imm.
    const float* xp = x + (size_t)(t & 7) * IN_F + kb + quad * 8;

    f32x4 acc = {0.f, 0.f, 0.f, 0.f};

#pragma unroll
    for (int s = 0; s < STEPS; ++s) {
        // ---- A fragment: bf16 truncation of x, 4 x v_perm ----
        union { unsigned u[4]; bf16x8 v; } a;
        const float4 v0 = *(const float4*)(xp + s * 32);
        const float4 v1 = *(const float4*)(xp + s * 32 + 4);
        a.u[0] = pack_bf_trunc(v0.x, v0.y);
        a.u[1] = pack_bf_trunc(v0.z, v0.w);
        a.u[2] = pack_bf_trunc(v1.x, v1.y);
        a.u[3] = pack_bf_trunc(v1.z, v1.w);

        // ---- B fragment: (w - z), exact small ints in bf16 ----
        // Byte-spread nibbles -> v_cvt_f32_ubyte0..3, sub, perm-pack.
        const unsigned q  = (unsigned)qv[s];
        const unsigned lo = q & 0x0f0f0f0fu;           // nibbles 0,2,4,6
        const unsigned hi = (q >> 4) & 0x0f0f0f0fu;    // nibbles 1,3,5,7
        union { unsigned u[4]; bf16x8 v; } b;
#pragma unroll
        for (int p = 0; p < 4; ++p) {
            const float f0 = (float)((lo >> (8 * p)) & 0xffu) - zf;  // k elem 2p
            const float f1 = (float)((hi >> (8 * p)) & 0xffu) - zf;  // k elem 2p+1
            b.u[p] = pack_bf_trunc(f0, f1);
        }

        acc = __builtin_amdgcn_mfma_f32_16x16x32_bf16(a.v, b.v, acc, 0, 0, 0);
    }

    // D rows 0..7 (quads 0,1) are the real x-rows; rows 8..15 are the t&7
    // duplicates -- discarded.
    if (quad < 2) {
        float* Pp = P + (size_t)blockIdx.y * (M * OUT_F);
        const int r0 = quad * 4;
#pragma unroll
        for (int r = 0; r < 4; ++r)
            Pp[(size_t)(r0 + r) * OUT_F + col] = acc[r];
    }
}

// ---------------- out[r][j] = bias[j] + s_j * sum_s P[s][r][j] ----------------
// 1 wave per block, 1 output per thread; 16 independent strided loads give
// enough ILP to hide L2/HBM latency at 1376 blocks.
__global__ __launch_bounds__(64) void gptq_reduce(
    const float* __restrict__ P, const float* __restrict__ sc,
    const float* __restrict__ bias, float* __restrict__ out)
{
    const int r = (int)blockIdx.y;
    const int j = (int)blockIdx.x * 64 + (int)threadIdx.x;   // 172*64 = 11008

    float acc = 0.0f;
#pragma unroll
    for (int s = 0; s < S_SLICES; ++s)
        acc += P[(size_t)s * (M * OUT_F) + (size_t)r * OUT_F + j];

    out[(size_t)r * OUT_F + j] = fmaf(sc[j], acc, bias[j]);
}

extern "C" void kernel_launch(void* const* d_in, const int* in_sizes, int n_in,
                              void* d_out, int out_size, void* d_ws, size_t ws_size,
                              hipStream_t stream) {
    const float* x    = (const float*)d_in[0];
    const int*   qw   = (const int*)d_in[1];
    const int*   qz   = (const int*)d_in[2];
    const float* sc   = (const float*)d_in[3];
    const float* bias = (const float*)d_in[4];
    float* out = (float*)d_out;

    float* P = (float*)d_ws;   // 16*8*11008*4 B = 5.6 MB

    hipLaunchKernelGGL(gptq_mfma_fused, dim3(OUT_F / 64, S_SLICES), dim3(256), 0,
                       stream, qw, x, qz, P);
    hipLaunchKernelGGL(gptq_reduce, dim3(OUT_F / 64, M), dim3(64), 0, stream,
                       P, sc, bias, out);
}

// Round 4
// 88.301 us; speedup vs baseline: 1.0852x; 1.0852x over previous
//
#include <hip/hip_runtime.h>

#define IN_F 4096
#define OUT_F 11008
#define M 8
#define S_SLICES 16
#define KPS (IN_F / S_SLICES)     // 256 k-values per slice
#define RPSL (KPS / 8)            // 32 packed qweight rows per slice
#define STEPS (KPS / 32)          // 8 MFMA K-steps per slice

typedef __bf16 bf16x8 __attribute__((ext_vector_type(8)));
typedef float  f32x4  __attribute__((ext_vector_type(4)));
typedef unsigned short us8 __attribute__((ext_vector_type(8)));

// bf16 truncation of fp32 (exact for small ints; consistent across kernels)
__device__ __forceinline__ float trunc_bf(float v) {
    return __uint_as_float(__float_as_uint(v) & 0xffff0000u);
}

// ---------------- prep: xb = bf16(x) with pad rows zeroed, rs[r] = sum_k bf16(x[r][k]) ----
// Merges round-0's rowsum_kernel + convert_x_kernel into ONE dispatch (they
// read the same x; saves one launch slot + one x pass). Branch is
// block-uniform (r per block), so the __syncthreads is safe.
__global__ __launch_bounds__(256) void prep_kernel(
    const float* __restrict__ x, unsigned short* __restrict__ xb, // (16, IN_F)
    float* __restrict__ rs)
{
    __shared__ float wsum[4];
    const int r = (int)blockIdx.x;          // 0..15
    const int t = (int)threadIdx.x;         // 0..255

    if (r < M) {
        const float4* xp = (const float4*)(x + (size_t)r * IN_F);
        float s = 0.0f;
#pragma unroll
        for (int c = 0; c < 2; ++c) {
            const int i = c * 256 + t;      // 8-float chunk index, 0..511
            const float4 v0 = xp[2 * i];
            const float4 v1 = xp[2 * i + 1];
            us8 o;
            o[0] = (unsigned short)(__float_as_uint(v0.x) >> 16);
            o[1] = (unsigned short)(__float_as_uint(v0.y) >> 16);
            o[2] = (unsigned short)(__float_as_uint(v0.z) >> 16);
            o[3] = (unsigned short)(__float_as_uint(v0.w) >> 16);
            o[4] = (unsigned short)(__float_as_uint(v1.x) >> 16);
            o[5] = (unsigned short)(__float_as_uint(v1.y) >> 16);
            o[6] = (unsigned short)(__float_as_uint(v1.z) >> 16);
            o[7] = (unsigned short)(__float_as_uint(v1.w) >> 16);
            *(us8*)(xb + (size_t)r * IN_F + (size_t)i * 8) = o;
            s += trunc_bf(v0.x) + trunc_bf(v0.y) + trunc_bf(v0.z) + trunc_bf(v0.w)
               + trunc_bf(v1.x) + trunc_bf(v1.y) + trunc_bf(v1.z) + trunc_bf(v1.w);
        }
#pragma unroll
        for (int off = 1; off < 64; off <<= 1) s += __shfl_xor(s, off, 64);
        if ((t & 63) == 0) wsum[t >> 6] = s;
        __syncthreads();
        if (t == 0) rs[r] = wsum[0] + wsum[1] + wsum[2] + wsum[3];
    } else {
#pragma unroll
        for (int c = 0; c < 2; ++c) {
            const int i = c * 256 + t;
            *(us8*)(xb + (size_t)r * IN_F + (size_t)i * 8) = (us8)0;
        }
    }
}

// ---------------- MFMA partial GEMM: P[slice][r][col] = sum_{k in slice} w[k][col]*x[r][k] --------
// Byte-identical to the round-0 harness-verified kernel (90.3 us session):
// no inline conversion, no zf in the hot loop -- lean B-build only.
// Layouts (m89/m91-verified): A[m=lane&15][k=quad*8+j]; B[k=quad*8+j][n=lane&15];
// D[row=quad*4+reg][col=lane&15]. B-frag k-run of 8 == nibbles of ONE qweight int32 (LSB-first).
__global__ __launch_bounds__(256) void gptq_mfma_kernel(
    const int* __restrict__ qw,             // (512, OUT_F)
    const unsigned short* __restrict__ xb,  // (16, IN_F) bf16 bits, rows 8..15 = 0
    float* __restrict__ P)                  // (S_SLICES, M, OUT_F)
{
    const int lane = threadIdx.x & 63;
    const int wv   = threadIdx.x >> 6;                 // wave 0..3
    const int t    = lane & 15;                        // = m (A) = n (B) = col (D)
    const int quad = lane >> 4;                        // 0..3
    const int col  = (blockIdx.x * 4 + wv) * 16 + t;   // 172*4*16 = 11008 exact
    const int i0   = blockIdx.y * RPSL;                // first packed row of slice
    const int kb   = blockIdx.y * KPS;                 // first k of slice

    // Issue ALL slice loads up front: 8 qweight (4 B/lane) + 8 A-frags (16 B/lane)
    // = 10 KB/wave in flight; vmcnt in-order drain then hits HBM latency once.
    int    qv [STEPS];
    bf16x8 afr[STEPS];
    const int* qcol = qw + (size_t)(i0 + quad) * OUT_F + col;
    const unsigned short* xrow = xb + (size_t)t * IN_F + kb + quad * 8;
#pragma unroll
    for (int s = 0; s < STEPS; ++s) {
        qv[s]  = qcol[(size_t)s * 4 * OUT_F];              // row i0 + s*4 + quad
        afr[s] = *(const bf16x8*)(xrow + s * 32);          // k = kb + s*32 + quad*8
    }

    f32x4 acc = {0.f, 0.f, 0.f, 0.f};
#pragma unroll
    for (int s = 0; s < STEPS; ++s) {
        union { unsigned short u[8]; bf16x8 v; } bf;
#pragma unroll
        for (int j = 0; j < 8; ++j) {
            const float f = (float)((qv[s] >> (4 * j)) & 15);   // nibble exact in bf16
            bf.u[j] = (unsigned short)(__float_as_uint(f) >> 16);
        }
        acc = __builtin_amdgcn_mfma_f32_16x16x32_bf16(afr[s], bf.v, acc, 0, 0, 0);
    }

    // D rows 0..7 are real x-rows (quads 0,1); rows 8..15 are the zero-pad.
    const int r0 = quad * 4;
    if (r0 < M) {
        float* Pp = P + (size_t)blockIdx.y * (M * OUT_F);
#pragma unroll
        for (int r = 0; r < 4; ++r)
            Pp[(size_t)(r0 + r) * OUT_F + col] = acc[r];
    }
}

// ---------------- out[r][j] = bias[j] + s_j*(sum_s P[s][r][j] - z_j*rowsum[r]) ----------------
__global__ __launch_bounds__(256) void reduce_kernel(
    const float* __restrict__ P, const float* __restrict__ rs,
    const int* __restrict__ qz, const float* __restrict__ sc,
    const float* __restrict__ bias, float* __restrict__ out)
{
    const int idx = blockIdx.x * 256 + threadIdx.x;
    const int j = idx % OUT_F;
    const int r = idx / OUT_F;

    float acc = 0.0f;
#pragma unroll
    for (int s = 0; s < S_SLICES; ++s)
        acc += P[(size_t)s * M * OUT_F + (size_t)r * OUT_F + j];

    const int zw = qz[j >> 3];
    const float z = (float)(((zw >> ((j & 7) * 4)) & 15) + 1);
    out[(size_t)r * OUT_F + j] = fmaf(sc[j], acc - z * rs[r], bias[j]);
}

extern "C" void kernel_launch(void* const* d_in, const int* in_sizes, int n_in,
                              void* d_out, int out_size, void* d_ws, size_t ws_size,
                              hipStream_t stream) {
    const float* x    = (const float*)d_in[0];
    const int*   qw   = (const int*)d_in[1];
    const int*   qz   = (const int*)d_in[2];
    const float* sc   = (const float*)d_in[3];
    const float* bias = (const float*)d_in[4];
    float* out = (float*)d_out;

    float*          P  = (float*)d_ws;                               // 5.6 MB
    unsigned short* xb = (unsigned short*)((char*)d_ws + (8u << 20));// 128 KB
    float*          rs = (float*)((char*)d_ws + (16u << 20));        // 32 B

    hipLaunchKernelGGL(prep_kernel, dim3(16), dim3(256), 0, stream, x, xb, rs);
    hipLaunchKernelGGL(gptq_mfma_kernel, dim3(OUT_F / 64, S_SLICES), dim3(256), 0, stream,
                       qw, xb, P);
    hipLaunchKernelGGL(reduce_kernel, dim3((M * OUT_F) / 256), dim3(256), 0, stream,
                       P, rs, qz, sc, bias, out);
}